// Round 3
// baseline (209.475 us; speedup 1.0000x reference)
//
#include <hip/hip_runtime.h>

// Involution2d: B=8, C=256, G=4 (Cpg=64), H=W=Ho=Wo=64, K=7, PAD=3, STRIDE=1.
// out[b, g*64+c, y, x] = sum_{kh,kw} in[b, g*64+c, y+kh-3, x+kw-3] * w[b,g,kh,kw,y,x] + bias[g*64+c]
//
// Round-3: attack the LDS pipe (was ~30us of the 64us dispatch: 688K b128
// wave-ops + 10.6M conflict cycles). Row-blocking R=2: thread computes
// 2 rows x 4 cols x 4 channels; looping s = r+kh means each staged input row
// is read ONCE and feeds both (r=0,kh=s) and (r=1,kh=s-1):
//   LDS per 32 outputs: 24 b128  (was 21 b128 per 4 outputs -> 2.8x less)
// Weight float4s stay shared across the 4 simultaneous channels (L2 weight
// traffic unchanged at 411MB). Staging is fully vectorized: halo at col 4
// makes global float4 -> ds_write_b128 16B-aligned; x-halo is always zero
// (image border), y-halo handled by gy bounds. Bank phases uniform for both
// staging writes and compute reads (stride 72).

#define BLK_X 16
#define BLK_Y 8
#define NTHR  128
#define NC    4                   // channels accumulated simultaneously
#define R     2                   // output rows per thread
#define TROWS (BLK_Y * R)         // 16 output rows per block
#define S_ROWS 22                 // TROWS + 6 halo
#define S_STRIDE 72               // 18 float4 per row (halo col 0..3 / 68..71)
#define S_CH (S_ROWS * S_STRIDE)  // 1584 floats per channel
#define SEGS_PER_CH (S_ROWS * 18) // 396 float4 segments per channel

__global__ __launch_bounds__(NTHR)
__attribute__((amdgpu_waves_per_eu(3)))
void involution_kernel(const float* __restrict__ in,
                       const float* __restrict__ w,
                       const float* __restrict__ bias,
                       float* __restrict__ out) {
    __shared__ float lds[NC * S_CH];   // 25,344 B -> 6 blocks/CU

    const int tx  = threadIdx.x;       // 0..15 (x-quad)
    const int ty  = threadIdx.y;       // 0..7  (row-pair)
    const int tid = ty * BLK_X + tx;
    const int x0  = tx * 4;
    const int Y0  = blockIdx.x * TROWS;
    const int c0  = blockIdx.y * NC;
    const int bz  = blockIdx.z;        // b*4 + g
    const int g   = bz & 3;

    const float* inb  = in  + (size_t)bz * 64 * 4096;
    float*       outb = out + (size_t)bz * 64 * 4096;

    // ---- stage NC channels, fully vectorized (float4 in, b128 to LDS) ----
    // segment t of a row covers lds cols 4t..4t+3; t=0 and t=17 are halo
    // (always zero: x out of image); t=1..16 map to gx = 4(t-1)..4(t-1)+3.
    #pragma unroll
    for (int ch = 0; ch < NC; ++ch) {
        const float* p = inb + (size_t)(c0 + ch) * 4096;
        float* l = lds + ch * S_CH;
        #pragma unroll
        for (int j = 0; j < 4; ++j) {
            int e = tid + j * NTHR;              // 0..511, guard < 396
            if (e < SEGS_PER_CH) {
                int row = e / 18;
                int t   = e - row * 18;
                int gy  = Y0 + row - 3;
                float4 v = make_float4(0.f, 0.f, 0.f, 0.f);
                if (t >= 1 && t <= 16 && gy >= 0 && gy < 64)
                    v = *(const float4*)(p + gy * 64 + (t - 1) * 4);
                *(float4*)(l + row * S_STRIDE + t * 4) = v;
            }
        }
    }
    __syncthreads();

    float acc[NC][R][4];
    #pragma unroll
    for (int c = 0; c < NC; ++c)
        #pragma unroll
        for (int r = 0; r < R; ++r)
            #pragma unroll
            for (int i = 0; i < 4; ++i) acc[c][r][i] = 0.f;

    // weight base for this thread's row pair (y = Y0 + 2*ty + r)
    const float* wb = w + (size_t)bz * 49 * 4096 + (Y0 + ty * R) * 64 + x0;

    // ---- s-loop: s = r + kh; staged row (ty*R + s) read once, feeds
    //      (r=0, kh=s) and (r=1, kh=s-1) ----
    #pragma unroll
    for (int s = 0; s < 8; ++s) {
        float4 wv0[7], wv1[7];
        if (s <= 6) {
            #pragma unroll
            for (int kw = 0; kw < 7; ++kw)
                wv0[kw] = *(const float4*)(wb + (size_t)(s * 7 + kw) * 4096);
        }
        if (s >= 1) {
            #pragma unroll
            for (int kw = 0; kw < 7; ++kw)
                wv1[kw] = *(const float4*)(wb + (size_t)((s - 1) * 7 + kw) * 4096 + 64);
        }
        #pragma unroll
        for (int c = 0; c < NC; ++c) {
            const float* lr = lds + c * S_CH + (ty * R + s) * S_STRIDE + x0;
            // window needed: cols x0+1 .. x0+10; 3 aligned b128 cover x0..x0+11
            float4 va = *(const float4*)(lr);
            float4 vb = *(const float4*)(lr + 4);
            float4 vc = *(const float4*)(lr + 8);
            float vals[12] = {va.x, va.y, va.z, va.w,
                              vb.x, vb.y, vb.z, vb.w,
                              vc.x, vc.y, vc.z, vc.w};
            if (s <= 6) {
                #pragma unroll
                for (int kw = 0; kw < 7; ++kw) {
                    acc[c][0][0] += vals[kw + 1] * wv0[kw].x;
                    acc[c][0][1] += vals[kw + 2] * wv0[kw].y;
                    acc[c][0][2] += vals[kw + 3] * wv0[kw].z;
                    acc[c][0][3] += vals[kw + 4] * wv0[kw].w;
                }
            }
            if (s >= 1) {
                #pragma unroll
                for (int kw = 0; kw < 7; ++kw) {
                    acc[c][1][0] += vals[kw + 1] * wv1[kw].x;
                    acc[c][1][1] += vals[kw + 2] * wv1[kw].y;
                    acc[c][1][2] += vals[kw + 3] * wv1[kw].z;
                    acc[c][1][3] += vals[kw + 4] * wv1[kw].w;
                }
            }
        }
    }

    // ---- epilogue ----
    #pragma unroll
    for (int c = 0; c < NC; ++c) {
        const float bv = bias[g * 64 + c0 + c];
        #pragma unroll
        for (int r = 0; r < R; ++r) {
            float4 o;
            o.x = acc[c][r][0] + bv;
            o.y = acc[c][r][1] + bv;
            o.z = acc[c][r][2] + bv;
            o.w = acc[c][r][3] + bv;
            *(float4*)(outb + (size_t)(c0 + c) * 4096
                       + (Y0 + ty * R + r) * 64 + x0) = o;
        }
    }
}

extern "C" void kernel_launch(void* const* d_in, const int* in_sizes, int n_in,
                              void* d_out, int out_size, void* d_ws, size_t ws_size,
                              hipStream_t stream) {
    const float* in   = (const float*)d_in[0];  // (8,256,64,64)
    const float* wgt  = (const float*)d_in[1];  // (8,4,7,7,64,64)
    const float* bias = (const float*)d_in[2];  // (256,)
    float* out = (float*)d_out;                 // (8,256,64,64)

    dim3 block(BLK_X, BLK_Y, 1);                 // 128 threads = 2 waves
    dim3 grid(64 / TROWS, 64 / NC, 32);          // (4, 16, 32) = 2048 blocks
    involution_kernel<<<grid, block, 0, stream>>>(in, wgt, bias, out);
}